// Round 3
// baseline (2826.186 us; speedup 1.0000x reference)
//
#include <hip/hip_runtime.h>

// ---------------------------------------------------------------------------
// NER CRF LSTM on MI355X. Round 3: zero-LDS recurrence loop.
//  - per-block flag counters + wave-parallel poll (no serialized atomics)
//  - MFMA A-fragments loaded directly from global (x: cached; h: cached, safe
//    because dispatch-start acquire invalidated L2 and first touch is post-flag)
//  - gates combined in-register via wave-column remap + Eklundh shfl transpose
//  - dual accumulator chains; weights held in AGPRs
// ws layout: emb_bf 32MB | h_hist 64MB | feats 1.5MB | flags 4KB.
// ---------------------------------------------------------------------------

#define B_ 64
#define T_ 512
#define E_ 512
#define H_ 512
#define NTAGS 12
#define START_ID_ 10
#define STOP_ID_ 11

typedef __attribute__((ext_vector_type(8))) short s8v;       // 8 x bf16 bits
typedef __attribute__((ext_vector_type(4))) float f32x4;     // MFMA acc
typedef __attribute__((ext_vector_type(2))) unsigned uint2v; // 8B store payload

__device__ __forceinline__ unsigned short f2bf(float f) {
    unsigned u = __float_as_uint(f);
    u += 0x7fffu + ((u >> 16) & 1u);           // RNE
    return (unsigned short)(u >> 16);
}
__device__ __forceinline__ float bf2f(unsigned short h) {
    return __uint_as_float(((unsigned)h) << 16);
}
__device__ __forceinline__ float sigm(float x) { return 1.f / (1.f + __expf(-x)); }
__device__ __forceinline__ float tanh_f(float x) { return 1.f - 2.f / (__expf(2.f * x) + 1.f); }

// MFMA: A from VGPR, B (weights) from AGPR, acc VGPR. volatile pins order.
__device__ __forceinline__ void mfma_av(f32x4& c, s8v a, s8v b) {
    asm volatile("v_mfma_f32_16x16x32_bf16 %0, %1, %2, %0" : "+v"(c) : "v"(a), "a"(b));
}

// LLC (device-coherent) primitives for cross-CU handoff.
__device__ __forceinline__ unsigned load_flag(const unsigned* p) {
    unsigned r;
    asm volatile("global_load_dword %0, %1, off sc0 sc1\n\ts_waitcnt vmcnt(0)"
                 : "=v"(r) : "v"(p) : "memory");
    return r;
}
__device__ __forceinline__ void store_flag(unsigned* p, unsigned v) {
    asm volatile("global_store_dword %0, %1, off sc0 sc1" :: "v"(p), "v"(v) : "memory");
}
__device__ __forceinline__ void store_llc_b64(unsigned short* p, uint2v v) {
    asm volatile("global_store_dwordx2 %0, %1, off sc0 sc1" :: "v"(p), "v"(v) : "memory");
}

// ---------------------------------------------------------------------------
// Kernel 1: embedding gather + fp32->bf16. One wave per (b,t) row.
// ---------------------------------------------------------------------------
__global__ __launch_bounds__(256) void embed_gather(
    const int* __restrict__ x, const float* __restrict__ embed,
    unsigned short* __restrict__ emb_bf)
{
    int wid  = blockIdx.x * 4 + (threadIdx.x >> 6);   // row = b*T + t, grid exact
    int lane = threadIdx.x & 63;
    int tok  = x[wid];
    const float* src = embed + (size_t)tok * E_ + lane * 8;
    float4 a = *(const float4*)src;
    float4 b = *(const float4*)(src + 4);
    s8v o;
    o[0] = (short)f2bf(a.x); o[1] = (short)f2bf(a.y);
    o[2] = (short)f2bf(a.z); o[3] = (short)f2bf(a.w);
    o[4] = (short)f2bf(b.x); o[5] = (short)f2bf(b.y);
    o[6] = (short)f2bf(b.z); o[7] = (short)f2bf(b.w);
    *(s8v*)(emb_bf + (size_t)wid * E_ + lane * 8) = o;
}

// ---------------------------------------------------------------------------
// Kernel 2: persistent BiLSTM. 256 blocks x 256 threads, 1 block/CU.
// team = blockIdx&7 -> (dir, batch-quarter of 16); member = blockIdx>>3 ->
// 16 h-dims. Wave w computes cols {gate g, j = j0 + w*4 + jl} (g=0..3, jl=0..3).
// ---------------------------------------------------------------------------
__global__ __launch_bounds__(256, 1) void lstm_persistent(
    const unsigned short* __restrict__ emb_bf,
    const float* __restrict__ Wih_f, const float* __restrict__ Whh_f,
    const float* __restrict__ bih_f, const float* __restrict__ bhh_f,
    const float* __restrict__ Wih_b, const float* __restrict__ Whh_b,
    const float* __restrict__ bih_b, const float* __restrict__ bhh_b,
    unsigned short* __restrict__ h_hist, unsigned* __restrict__ bar)
{
    const int team   = blockIdx.x & 7;
    const int member = blockIdx.x >> 3;      // 0..31
    const int dir = team & 1;
    const int b0  = (team >> 1) * 16;        // batch quarter base
    const int j0  = member * 16;             // h-dim base
    const int tid  = threadIdx.x;
    const int wave = tid >> 6;
    const int lane = tid & 63;

    // fragment lane mapping (A and B inputs): idx = lane&15, k-sub = (lane>>4)*8
    const int fr = lane & 15;
    const int fk = (lane >> 4) * 8;
    // D-output ownership after Eklundh transpose:
    const int kgrp  = lane >> 4;
    const int g_own = (lane >> 2) & 3;
    const int jloc  = lane & 3;
    const int b_own = b0 + kgrp * 4 + g_own;         // batch row this thread owns
    const int j_own = j0 + wave * 4 + jloc;          // absolute h-dim (0..511)

    const float* Wih = dir ? Wih_b : Wih_f;
    const float* Whh = dir ? Whh_b : Whh_f;
    const float* bih = dir ? bih_b : bih_f;
    const float* bhh = dir ? bhh_b : bhh_f;

    // ---- weight B-fragments (one-time). col n=fr -> gate (n>>2), j = j0+w*4+(n&3)
    const int wrow = (fr >> 2) * 512 + j0 + wave * 4 + (fr & 3);
    const float* whr = Whh + (size_t)wrow * 512;
    const float* wxr = Wih + (size_t)wrow * 512;
    s8v bh[16], bx[16];
#pragma unroll
    for (int kk = 0; kk < 16; kk++) {
        s8v v, w;
#pragma unroll
        for (int j = 0; j < 8; j++) {
            v[j] = (short)f2bf(whr[kk * 32 + fk + j]);
            w[j] = (short)f2bf(wxr[kk * 32 + fk + j]);
        }
        bh[kk] = v; bx[kk] = w;
    }

    float bias_[4];
#pragma unroll
    for (int r = 0; r < 4; r++) bias_[r] = bih[r * 512 + j_own] + bhh[r * 512 + j_own];

    float c_state = 0.f;
    unsigned* flags = bar + team * 32;
    const unsigned short* xrow0 = emb_bf + (size_t)(b0 + fr) * (T_ * E_) + fk;

    for (int s = 0; s < T_; s++) {
        const int t = dir ? (T_ - 1 - s) : s;

        // ---- x fragments direct from global (cached) + x MFMAs (pre-poll) ----
        const unsigned short* xp = xrow0 + (size_t)t * E_;
        s8v xa[16];
#pragma unroll
        for (int kk = 0; kk < 16; kk++) xa[kk] = *(const s8v*)(xp + kk * 32);
        f32x4 accA = {0.f, 0.f, 0.f, 0.f}, accB = {0.f, 0.f, 0.f, 0.f};
#pragma unroll
        for (int kk = 0; kk < 8; kk++) {
            mfma_av(accA, xa[2 * kk],     bx[2 * kk]);
            mfma_av(accB, xa[2 * kk + 1], bx[2 * kk + 1]);
        }

        if (s > 0) {
            // ---- wave-parallel poll: all 32 member flags >= s ----
            const unsigned su = (unsigned)s;
            for (;;) {
                unsigned fv = load_flag(flags + (lane & 31));
                if (__ballot(fv < su) == 0ull) break;
            }
            // ---- h fragments direct from global (cached; safe post-flag) ----
            const int tprev = dir ? (t + 1) : (t - 1);
            const unsigned short* hp = h_hist +
                (((size_t)dir * T_ + tprev) * B_ + (b0 + fr)) * H_ + fk;
            s8v ha[16];
#pragma unroll
            for (int kk = 0; kk < 16; kk++) ha[kk] = *(const s8v*)(hp + kk * 32);
#pragma unroll
            for (int kk = 0; kk < 8; kk++) {
                mfma_av(accA, ha[2 * kk],     bh[2 * kk]);
                mfma_av(accB, ha[2 * kk + 1], bh[2 * kk + 1]);
            }
        }

        float acc[4];
#pragma unroll
        for (int r = 0; r < 4; r++) acc[r] = accA[r] + accB[r];

        // ---- Eklundh 4x4 transpose across g (lane masks 4, 8) ----
        // in: acc[r] = (gate g_own, batch kgrp*4+r); out: gate[r] = gate r of b_own
        float p0 = __shfl_xor(acc[0], 4, 64);
        float p1 = __shfl_xor(acc[1], 4, 64);
        float p2 = __shfl_xor(acc[2], 4, 64);
        float p3 = __shfl_xor(acc[3], 4, 64);
        const bool glo = (g_own & 1);
        float m1_0 = glo ? p1 : acc[0];
        float m1_1 = glo ? acc[1] : p0;
        float m1_2 = glo ? p3 : acc[2];
        float m1_3 = glo ? acc[3] : p2;
        float q0 = __shfl_xor(m1_0, 8, 64);
        float q1 = __shfl_xor(m1_1, 8, 64);
        float q2 = __shfl_xor(m1_2, 8, 64);
        float q3 = __shfl_xor(m1_3, 8, 64);
        const bool ghi = (g_own >> 1) & 1;
        float gi = (ghi ? q2   : m1_0) + bias_[0];
        float gf = (ghi ? q3   : m1_1) + bias_[1];
        float gg = (ghi ? m1_2 : q0)   + bias_[2];
        float go = (ghi ? m1_3 : q1)   + bias_[3];

        // ---- activations; thread owns (b_own, j_own) ----
        c_state = sigm(gf) * c_state + sigm(gi) * tanh_f(gg);
        float hv = sigm(go) * tanh_f(c_state);

        // ---- pack 4 bf16 along j via shfl, one 8B write-through store ----
        unsigned hb = (unsigned)f2bf(hv) & 0xffffu;
        unsigned u01 = hb | (((unsigned)__shfl_xor((int)hb, 1, 64) & 0xffffu) << 16);
        unsigned u23 = (unsigned)__shfl_xor((int)u01, 2, 64);
        if (jloc == 0) {
            uint2v v2; v2[0] = u01; v2[1] = u23;
            store_llc_b64(h_hist +
                (((size_t)dir * T_ + t) * B_ + b_own) * H_ + j0 + wave * 4, v2);
        }
        asm volatile("s_waitcnt vmcnt(0)" ::: "memory");   // own stores acked at LLC
        __syncthreads();                                    // all waves acked
        if (tid == 0) store_flag(flags + member, (unsigned)(s + 1));
    }
}

// ---------------------------------------------------------------------------
// Kernel 3: feats[b,t,k] = [h_f|h_b] . W_out[k] + b_out[k].
// 1024 blocks; each wave handles 8 rows (W_out LDS staging amortized 32x).
// ---------------------------------------------------------------------------
__global__ __launch_bounds__(256) void feats_kernel(
    const unsigned short* __restrict__ h_hist,
    const float* __restrict__ W_out, const float* __restrict__ b_out,
    float* __restrict__ feats)
{
    __shared__ float wlds[NTAGS * 1024];
    __shared__ float blds[NTAGS];
    for (int i = threadIdx.x; i < NTAGS * 1024; i += 256) wlds[i] = W_out[i];
    if (threadIdx.x < NTAGS) blds[threadIdx.x] = b_out[threadIdx.x];
    __syncthreads();

    int lane = threadIdx.x & 63;
    int row0 = blockIdx.x * 32 + (threadIdx.x >> 6) * 8;
    for (int rr = 0; rr < 8; rr++) {
        int wid = row0 + rr;                 // row = b*T + t
        int b = wid >> 9, t = wid & 511;
        s8v vf = *(const s8v*)(h_hist + (((size_t)0 * T_ + t) * B_ + b) * H_ + lane * 8);
        s8v vb = *(const s8v*)(h_hist + (((size_t)1 * T_ + t) * B_ + b) * H_ + lane * 8);
        float xf[8], xb[8];
#pragma unroll
        for (int j = 0; j < 8; j++) {
            xf[j] = bf2f((unsigned short)vf[j]);
            xb[j] = bf2f((unsigned short)vb[j]);
        }
#pragma unroll
        for (int k = 0; k < NTAGS; k++) {
            float acc = 0.f;
#pragma unroll
            for (int j = 0; j < 8; j++) acc += xf[j] * wlds[k * 1024 + lane * 8 + j];
#pragma unroll
            for (int j = 0; j < 8; j++) acc += xb[j] * wlds[k * 1024 + 512 + lane * 8 + j];
#pragma unroll
            for (int off = 32; off > 0; off >>= 1) acc += __shfl_xor(acc, off, 64);
            if (lane == 0) feats[(size_t)wid * NTAGS + k] = acc + blds[k];
        }
    }
}

// ---------------------------------------------------------------------------
// Kernel 4: Viterbi. One wave per batch item; lane j<12 owns tag j.
// ---------------------------------------------------------------------------
__global__ __launch_bounds__(64) void viterbi_kernel(
    const float* __restrict__ feats, const float* __restrict__ trans,
    float* __restrict__ out)
{
    const int b = blockIdx.x;
    const int j = threadIdx.x;
    const int jj = (j < NTAGS) ? j : 0;    // safe index for inactive lanes
    __shared__ unsigned char bp[T_][NTAGS];
    __shared__ float flds[T_ * NTAGS];     // 24KB

    {
        const float4* src = (const float4*)(feats + (size_t)b * T_ * NTAGS);
        float4* dst = (float4*)flds;
        for (int i = j; i < T_ * NTAGS / 4; i += 64) dst[i] = src[i];
    }
    __syncthreads();

    float trow[NTAGS];
#pragma unroll
    for (int p = 0; p < NTAGS; p++) trow[p] = trans[jj * NTAGS + p];
    float fv = (j == START_ID_) ? 0.f : -10000.f;

    for (int t = 0; t < T_; t++) {
        float feat = flds[t * NTAGS + jj];
        float best = -3.4e38f; int bestp = 0;
#pragma unroll
        for (int p = 0; p < NTAGS; p++) {
            float sp = __shfl(fv, p, 64) + trow[p];    // all lanes participate
            if (sp > best) { best = sp; bestp = p; }   // strict > == argmax-first
        }
        fv = best + feat;
        if (j < NTAGS) bp[t][j] = (unsigned char)bestp;
    }

    float term = (j < NTAGS) ? (fv + trans[STOP_ID_ * NTAGS + jj]) : -3.4e38f;
    float best = -3.4e38f; int bt = 0;
#pragma unroll
    for (int p = 0; p < NTAGS; p++) {
        float v = __shfl(term, p, 64);
        if (v > best) { best = v; bt = p; }
    }
    __syncthreads();
    if (j == 0) {
        out[b] = best;
        int tag = bt;
        for (int t = T_ - 1; t >= 0; t--) {
            out[B_ + (size_t)b * T_ + t] = (float)tag;
            tag = bp[t][tag];
        }
    }
}

// ---------------------------------------------------------------------------
extern "C" void kernel_launch(void* const* d_in, const int* in_sizes, int n_in,
                              void* d_out, int out_size, void* d_ws, size_t ws_size,
                              hipStream_t stream)
{
    (void)in_sizes; (void)n_in; (void)out_size; (void)ws_size;
    const int*   x     = (const int*)  d_in[0];
    const float* embed = (const float*)d_in[1];
    const float* Wih_f = (const float*)d_in[2];
    const float* Whh_f = (const float*)d_in[3];
    const float* bih_f = (const float*)d_in[4];
    const float* bhh_f = (const float*)d_in[5];
    const float* Wih_b = (const float*)d_in[6];
    const float* Whh_b = (const float*)d_in[7];
    const float* bih_b = (const float*)d_in[8];
    const float* bhh_b = (const float*)d_in[9];
    const float* W_out = (const float*)d_in[10];
    const float* b_out = (const float*)d_in[11];
    const float* trans = (const float*)d_in[12];

    char* ws = (char*)d_ws;
    const size_t EMB_BYTES  = (size_t)B_ * T_ * E_ * 2;       // 32 MB
    const size_t HIST_BYTES = (size_t)2 * T_ * B_ * H_ * 2;   // 64 MB
    const size_t FEAT_BYTES = (size_t)B_ * T_ * NTAGS * 4;    // 1.5 MB
    unsigned short* emb_bf = (unsigned short*)(ws);
    unsigned short* h_hist = (unsigned short*)(ws + EMB_BYTES);
    float*          feats  = (float*)(ws + EMB_BYTES + HIST_BYTES);
    unsigned*       bar    = (unsigned*)(ws + EMB_BYTES + HIST_BYTES + FEAT_BYTES);

    hipMemsetAsync(bar, 0, 4096, stream);
    embed_gather<<<dim3(8192), dim3(256), 0, stream>>>(x, embed, emb_bf);
    lstm_persistent<<<dim3(256), dim3(256), 0, stream>>>(emb_bf,
        Wih_f, Whh_f, bih_f, bhh_f, Wih_b, Whh_b, bih_b, bhh_b, h_hist, bar);
    feats_kernel<<<dim3(1024), dim3(256), 0, stream>>>(h_hist, W_out, b_out, feats);
    viterbi_kernel<<<dim3(B_), dim3(64), 0, stream>>>(feats, trans, (float*)d_out);
}